// Round 12
// baseline (485.592 us; speedup 1.0000x reference)
//
#include <hip/hip_runtime.h>
#include <hip/hip_bf16.h>
#include <stdint.h>

#define H 128
#define NPB  224      // nodes per bucket
#define NBK  448      // bucket slots (NB=447 actual)
#define BCAP 6144     // max edges per bucket in LDS sort (mean ~3584)
#define NBLK 128      // partition blocks

typedef __attribute__((ext_vector_type(8))) short bf16x8;
typedef __attribute__((ext_vector_type(4))) float f32x4;

__device__ __forceinline__ unsigned pack_bf16x2(float a, float b){
  unsigned ua = __float_as_uint(a);
  unsigned ub = __float_as_uint(b);
  unsigned ra = (ua + 0x7fffu + ((ua >> 16) & 1u)) >> 16;   // RNE round to bf16
  unsigned rb = (ub + 0x7fffu + ((ub >> 16) & 1u)) >> 16;
  return ra | (rb << 16);
}
__device__ __forceinline__ float bf_lo(unsigned u){ return __uint_as_float(u << 16); }
__device__ __forceinline__ float bf_hi(unsigned u){ return __uint_as_float(u & 0xffff0000u); }

// h0 = pack_bf16(PQ @ W_in + b_in) ; V = (1,0).  h stored as bf16x2 (64 uints/node).
__global__ void init_kernel(const float* __restrict__ PQ, const float* __restrict__ Win,
                            const float* __restrict__ bin, unsigned* __restrict__ h,
                            float* __restrict__ V, int N){
  int lane = threadIdx.x & 63;
  int wid  = (blockIdx.x * blockDim.x + threadIdx.x) >> 6;
  int nw   = (gridDim.x * blockDim.x) >> 6;
  int c0 = 2*lane, c1 = c0 + 1;
  float w00 = Win[c0], w01 = Win[c1], w10 = Win[H+c0], w11 = Win[H+c1];
  float b0 = bin[c0], b1 = bin[c1];
  for (int n = wid; n < N; n += nw){
    float p0 = PQ[2*n], p1 = PQ[2*n+1];
    float h0 = p0*w00 + p1*w10 + b0;
    float h1 = p0*w01 + p1*w11 + b1;
    h[(size_t)n*64 + lane] = pack_bf16x2(h0, h1);
    if (lane == 0){ V[2*n] = 1.0f; V[2*n+1] = 0.0f; }
  }
}

// ---- atomic-free bucketed partition (radix-partition 3-pass) ----
__global__ void countA_kernel(const int* __restrict__ recv, int* __restrict__ cmat, int E){
  __shared__ int hist[NBK];
  int t = threadIdx.x;
  for (int b = t; b < NBK; b += 256) hist[b] = 0;
  __syncthreads();
  int chunk = (E + NBLK - 1) / NBLK;
  int lo = blockIdx.x * chunk, hi = min(E, lo + chunk);
  for (int i = lo + t; i < hi; i += 256)
    atomicAdd(&hist[recv[i]/NPB], 1);
  __syncthreads();
  for (int b = t; b < NBK; b += 256) cmat[blockIdx.x*NBK + b] = hist[b];
}

__global__ void cscan_kernel(const int* __restrict__ cmat, int* __restrict__ gofs,
                             int* __restrict__ bbase, int* __restrict__ rowptr,
                             int NB, int N, int E){
  __shared__ int s[512];
  int t = threadIdx.x;
  int tot = 0;
  if (t < NB)
    for (int k = 0; k < NBLK; ++k) tot += cmat[k*NBK + t];
  s[t] = tot; __syncthreads();
  #pragma unroll
  for (int off = 1; off < 512; off <<= 1){
    int x = (t >= off) ? s[t-off] : 0;
    __syncthreads();
    s[t] += x;
    __syncthreads();
  }
  int run = s[t] - tot;       // exclusive
  if (t < NB){
    bbase[t] = run;
    for (int k = 0; k < NBLK; ++k){
      gofs[k*NBK + t] = run;
      run += cmat[k*NBK + t];
    }
  }
  if (t == 0){ bbase[NB] = E; rowptr[N] = E; }
}

__global__ void scatterC_kernel(const int* __restrict__ recv, const int* __restrict__ send,
                                const int* __restrict__ gofs,
                                unsigned long long* __restrict__ ebuf, int E){
  __shared__ int cur[NBK];
  int t = threadIdx.x;
  for (int b = t; b < NBK; b += 256) cur[b] = gofs[blockIdx.x*NBK + b];
  __syncthreads();
  int chunk = (E + NBLK - 1) / NBLK;
  int lo = blockIdx.x * chunk, hi = min(E, lo + chunk);
  for (int i = lo + t; i < hi; i += 256){
    int r = recv[i];
    int b = r / NPB;
    int rloc = r - b*NPB;
    int pos = atomicAdd(&cur[b], 1);
    ebuf[pos] = ((unsigned long long)(unsigned)send[i] << 32)
              | ((unsigned long long)(unsigned)rloc << 24)
              | (unsigned long long)(unsigned)i;
  }
}

// per-bucket LDS counting sort -> dense ssort/eid + rowptr
__global__ void bsort_kernel(const unsigned long long* __restrict__ ebuf,
                             const int* __restrict__ bbase,
                             int* __restrict__ ssort, int* __restrict__ eid,
                             int* __restrict__ rowptr, int N, int NB){
  __shared__ unsigned long long se[BCAP];
  __shared__ int sdeg[256];
  __shared__ int scur[256];
  int b = blockIdx.x;
  int t = threadIdx.x;
  int base = bbase[b];
  int cnt  = bbase[b+1] - base;
  if (cnt > BCAP) cnt = BCAP;       // statistically unreachable for uniform input
  sdeg[t] = 0;
  __syncthreads();
  for (int i = t; i < cnt; i += 256){
    unsigned long long v = ebuf[base + i];
    se[i] = v;
    atomicAdd(&sdeg[(int)((v >> 24) & 0xFF)], 1);
  }
  __syncthreads();
  int own = sdeg[t];
  #pragma unroll
  for (int off = 1; off < 256; off <<= 1){
    int x = (t >= off) ? sdeg[t-off] : 0;
    __syncthreads();
    sdeg[t] += x;
    __syncthreads();
  }
  int excl = sdeg[t] - own;
  scur[t] = excl;
  int node0 = b*NPB;
  if (t < NPB && node0 + t < N) rowptr[node0 + t] = base + excl;
  __syncthreads();
  for (int i = t; i < cnt; i += 256){
    unsigned long long v = se[i];
    int off = atomicAdd(&scur[(int)((v >> 24) & 0xFF)], 1);
    ssort[base + off] = (int)(v >> 32);
    eid[base + off]   = (int)(v & 0xFFFFFF);
  }
}

// Pre-pack Wh (rows 2..129 of Wmsg) into per-lane MFMA B-fragment order, bf16x2.
__global__ void wprep_kernel(const float* __restrict__ Wmsg, unsigned* __restrict__ Wb, int L){
  int t = blockIdx.x*blockDim.x + threadIdx.x;
  if (t >= L*2048) return;
  int layer = t >> 11;
  int f = t & 2047;
  int ct   = f >> 8;
  int ks   = (f >> 6) & 3;
  int lane = f & 63;
  int col = ct*16 + (lane & 15);
  int kbase = ks*32 + (lane >> 4)*8;
  const float* Wl = Wmsg + (size_t)layer*134*H + 2*H;   // Wh rows
  unsigned u0 = pack_bf16x2(Wl[(size_t)(kbase+0)*H + col], Wl[(size_t)(kbase+1)*H + col]);
  unsigned u1 = pack_bf16x2(Wl[(size_t)(kbase+2)*H + col], Wl[(size_t)(kbase+3)*H + col]);
  unsigned u2 = pack_bf16x2(Wl[(size_t)(kbase+4)*H + col], Wl[(size_t)(kbase+5)*H + col]);
  unsigned u3 = pack_bf16x2(Wl[(size_t)(kbase+6)*H + col], Wl[(size_t)(kbase+7)*H + col]);
  uint4* dst = reinterpret_cast<uint4*>(Wb) + (size_t)layer*2048 + f;
  *dst = make_uint4(u0, u1, u2, u3);
}

// msrc = pack_bf16( h @ Wh  +  V @ Wv + b )  via MFMA (16 nodes/wave).
__global__ void node_msg_mfma(const float* __restrict__ V, const unsigned* __restrict__ h,
                              const float* __restrict__ Wmsg_l, const float* __restrict__ bmsg_l,
                              const unsigned* __restrict__ Wb_l, unsigned* __restrict__ msrc, int N){
  int lane = threadIdx.x & 63;
  int gw   = (blockIdx.x*blockDim.x + threadIdx.x) >> 6;
  int nwv  = (gridDim.x*blockDim.x) >> 6;
  int row = lane & 15, kg = lane >> 4;
  int ntiles = N >> 4;                      // N divisible by 16
  const bf16x8* wb = reinterpret_cast<const bf16x8*>(Wb_l);
  for (int t = gw; t < ntiles; t += nwv){
    int node0 = t << 4;
    const bf16x8* hrow = reinterpret_cast<const bf16x8*>(h + (size_t)(node0 + row)*64);
    bf16x8 a[4];
    #pragma unroll
    for (int ks = 0; ks < 4; ++ks) a[ks] = hrow[ks*4 + kg];
    float2 vv[4];
    #pragma unroll
    for (int r = 0; r < 4; ++r)
      vv[r] = *reinterpret_cast<const float2*>(V + 2*(node0 + kg*4 + r));
    #pragma unroll
    for (int ct = 0; ct < 8; ++ct){
      f32x4 acc = {0.f, 0.f, 0.f, 0.f};
      #pragma unroll
      for (int ks = 0; ks < 4; ++ks){
        bf16x8 b = wb[(ct*4 + ks)*64 + lane];
        acc = __builtin_amdgcn_mfma_f32_16x16x32_bf16(a[ks], b, acc, 0, 0, 0);
      }
      int col = ct*16 + row;
      float wv0 = Wmsg_l[col], wv1 = Wmsg_l[H + col], bb = bmsg_l[col];
      #pragma unroll
      for (int r = 0; r < 4; ++r){
        float o = acc[r] + vv[r].x*wv0 + vv[r].y*wv1 + bb;
        float oh = __shfl_xor(o, 1, 64);
        if (!(lane & 1)){
          int nr = node0 + kg*4 + r;
          msrc[(size_t)nr*64 + ct*8 + (row >> 1)] = pack_bf16x2(o, oh);
        }
      }
    }
  }
}

// per receiver node: acc = sum_e m_src[s_e] (+ ef term); h=relu(acc) bf16;
// dV = h@W_out + b_out; V += dV.  One wave per node; 64-edge chunks with
// full-wave broadcast gather, x8 unroll (8 VMEM in flight; degree~16 -> 2 rounds).
template<bool FIRST, bool WRITEH>
__global__ void agg_update_kernel(const unsigned* __restrict__ msrc,
                                  const int* __restrict__ rowptr,
                                  const int* __restrict__ eid,
                                  const int* __restrict__ ssort,
                                  const float* __restrict__ ef,
                                  const float* __restrict__ Wmsg_l,
                                  const float* __restrict__ Wout_l,
                                  const float* __restrict__ bout_l,
                                  const float* __restrict__ Vin,
                                  float* __restrict__ Vout,
                                  unsigned* __restrict__ h,
                                  float4* __restrict__ efsum, int N){
  int lane = threadIdx.x & 63;
  int wid  = (blockIdx.x*blockDim.x + threadIdx.x) >> 6;
  int nw   = (gridDim.x*blockDim.x) >> 6;
  int c0 = 2*lane, c1 = c0 + 1;
  float We00 = Wmsg_l[(size_t)130*H + c0], We01 = Wmsg_l[(size_t)130*H + c1];
  float We10 = Wmsg_l[(size_t)131*H + c0], We11 = Wmsg_l[(size_t)131*H + c1];
  float We20 = Wmsg_l[(size_t)132*H + c0], We21 = Wmsg_l[(size_t)132*H + c1];
  float We30 = Wmsg_l[(size_t)133*H + c0], We31 = Wmsg_l[(size_t)133*H + c1];
  float Wo00 = Wout_l[c0*2], Wo01 = Wout_l[c0*2+1];
  float Wo10 = Wout_l[c1*2], Wo11 = Wout_l[c1*2+1];
  float bo0 = bout_l[0], bo1 = bout_l[1];
  for (int n = wid; n < N; n += nw){
    int beg = rowptr[n], end = rowptr[n+1];
    float acc0 = 0.f, acc1 = 0.f;
    float sfx = 0.f, sfy = 0.f, sfz = 0.f, sfw = 0.f;
    for (int c = beg; c < end; c += 64){
      int inlane = (c + lane < end);
      int sv = inlane ? ssort[c + lane] : 0;
      if (FIRST && inlane){
        int e = eid[c + lane];
        float4 f = *reinterpret_cast<const float4*>(ef + (size_t)e*4);
        sfx += f.x; sfy += f.y; sfz += f.z; sfw += f.w;
      }
      int kmax = min(64, end - c);
      int j = 0;
      for (; j + 8 <= kmax; j += 8){
        int s0 = __shfl(sv, j,   64);
        int s1 = __shfl(sv, j+1, 64);
        int s2 = __shfl(sv, j+2, 64);
        int s3 = __shfl(sv, j+3, 64);
        int s4 = __shfl(sv, j+4, 64);
        int s5 = __shfl(sv, j+5, 64);
        int s6 = __shfl(sv, j+6, 64);
        int s7 = __shfl(sv, j+7, 64);
        unsigned u0 = msrc[(size_t)s0*64 + lane];
        unsigned u1 = msrc[(size_t)s1*64 + lane];
        unsigned u2 = msrc[(size_t)s2*64 + lane];
        unsigned u3 = msrc[(size_t)s3*64 + lane];
        unsigned u4 = msrc[(size_t)s4*64 + lane];
        unsigned u5 = msrc[(size_t)s5*64 + lane];
        unsigned u6 = msrc[(size_t)s6*64 + lane];
        unsigned u7 = msrc[(size_t)s7*64 + lane];
        acc0 += bf_lo(u0) + bf_lo(u1) + bf_lo(u2) + bf_lo(u3)
              + bf_lo(u4) + bf_lo(u5) + bf_lo(u6) + bf_lo(u7);
        acc1 += bf_hi(u0) + bf_hi(u1) + bf_hi(u2) + bf_hi(u3)
              + bf_hi(u4) + bf_hi(u5) + bf_hi(u6) + bf_hi(u7);
      }
      for (; j + 4 <= kmax; j += 4){
        int s0 = __shfl(sv, j,   64);
        int s1 = __shfl(sv, j+1, 64);
        int s2 = __shfl(sv, j+2, 64);
        int s3 = __shfl(sv, j+3, 64);
        unsigned u0 = msrc[(size_t)s0*64 + lane];
        unsigned u1 = msrc[(size_t)s1*64 + lane];
        unsigned u2 = msrc[(size_t)s2*64 + lane];
        unsigned u3 = msrc[(size_t)s3*64 + lane];
        acc0 += bf_lo(u0) + bf_lo(u1) + bf_lo(u2) + bf_lo(u3);
        acc1 += bf_hi(u0) + bf_hi(u1) + bf_hi(u2) + bf_hi(u3);
      }
      for (; j < kmax; ++j){
        int s = __shfl(sv, j, 64);
        unsigned u = msrc[(size_t)s*64 + lane];
        acc0 += bf_lo(u); acc1 += bf_hi(u);
      }
    }
    if (FIRST){
      #pragma unroll
      for (int off = 32; off > 0; off >>= 1){
        sfx += __shfl_xor(sfx, off, 64);
        sfy += __shfl_xor(sfy, off, 64);
        sfz += __shfl_xor(sfz, off, 64);
        sfw += __shfl_xor(sfw, off, 64);
      }
      if (lane == 0) efsum[n] = make_float4(sfx, sfy, sfz, sfw);
    } else {
      float4 f = efsum[n];
      sfx = f.x; sfy = f.y; sfz = f.z; sfw = f.w;
    }
    acc0 += sfx*We00 + sfy*We10 + sfz*We20 + sfw*We30;
    acc1 += sfx*We01 + sfy*We11 + sfz*We21 + sfw*We31;
    float a0 = fmaxf(acc0, 0.f), a1 = fmaxf(acc1, 0.f);
    if (WRITEH) h[(size_t)n*64 + lane] = pack_bf16x2(a0, a1);
    float p0 = a0*Wo00 + a1*Wo10;
    float p1 = a0*Wo01 + a1*Wo11;
    #pragma unroll
    for (int off = 32; off > 0; off >>= 1){
      p0 += __shfl_xor(p0, off, 64);
      p1 += __shfl_xor(p1, off, 64);
    }
    if (lane == 0){
      float v0 = Vin[2*n], v1 = Vin[2*n+1];
      Vout[2*n]   = v0 + p0 + bo0;
      Vout[2*n+1] = v1 + p1 + bo1;
    }
  }
}

extern "C" void kernel_launch(void* const* d_in, const int* in_sizes, int n_in,
                              void* d_out, int out_size, void* d_ws, size_t ws_size,
                              hipStream_t stream){
  const float* PQ      = (const float*)d_in[0];
  const int*   senders = (const int*)  d_in[1];
  const int*   recv    = (const int*)  d_in[2];
  const float* ef      = (const float*)d_in[3];
  const float* Win     = (const float*)d_in[4];
  const float* bin     = (const float*)d_in[5];
  const float* Wmsg    = (const float*)d_in[6];
  const float* bmsg    = (const float*)d_in[7];
  const float* Wout    = (const float*)d_in[8];
  const float* bout    = (const float*)d_in[9];
  int N = in_sizes[0] / 2;
  int E = in_sizes[1];
  int L = in_sizes[7] / H;          // 3 layers
  int NB = (N + NPB - 1) / NPB;     // 447 buckets

  char* base = (char*)d_ws;
  size_t off = 0;
  auto alloc = [&](size_t bytes)->char*{
    char* p = base + off; off += (bytes + 255) & ~(size_t)255; return p;
  };
  unsigned* h      = (unsigned*)alloc((size_t)N*64*4);   // bf16x2-packed
  unsigned* msrc   = (unsigned*)alloc((size_t)N*64*4);
  float*    V      = (float*)   alloc((size_t)N*2*4);
  int*      rowptr = (int*)     alloc((size_t)(N+1)*4);
  int*      eid    = (int*)     alloc((size_t)E*4);
  int*      ssort  = (int*)     alloc((size_t)E*4);
  unsigned long long* ebuf = (unsigned long long*)alloc((size_t)E*8);
  float4*   efsum  = (float4*)  alloc((size_t)N*16);
  int*      cmat   = (int*)     alloc((size_t)NBLK*NBK*4);
  int*      gofs   = (int*)     alloc((size_t)NBLK*NBK*4);
  int*      bbase  = (int*)     alloc((size_t)(NB+1)*4);
  unsigned* Wb     = (unsigned*)alloc((size_t)L*2048*16); // MFMA B fragments
  if (off > ws_size) return;

  init_kernel<<<2048, 256, 0, stream>>>(PQ, Win, bin, h, V, N);
  countA_kernel<<<NBLK, 256, 0, stream>>>(recv, cmat, E);
  cscan_kernel<<<1, 512, 0, stream>>>(cmat, gofs, bbase, rowptr, NB, N, E);
  scatterC_kernel<<<NBLK, 256, 0, stream>>>(recv, senders, gofs, ebuf, E);
  bsort_kernel<<<NB, 256, 0, stream>>>(ebuf, bbase, ssort, eid, rowptr, N, NB);
  wprep_kernel<<<(L*2048 + 255)/256, 256, 0, stream>>>(Wmsg, Wb, L);

  for (int l = 0; l < L; ++l){
    const float* Wmsg_l = Wmsg + (size_t)l*134*H;
    const float* bmsg_l = bmsg + (size_t)l*H;
    const float* Wout_l = Wout + (size_t)l*H*2;
    const float* bout_l = bout + (size_t)l*2;
    const unsigned* Wb_l = Wb + (size_t)l*2048*4;
    node_msg_mfma<<<1568, 256, 0, stream>>>(V, h, Wmsg_l, bmsg_l, Wb_l, msrc, N);
    float* Vout = (l == L-1) ? (float*)d_out : V;
    if (l == 0)
      agg_update_kernel<true, true><<<2048, 256, 0, stream>>>(msrc, rowptr, eid, ssort, ef,
                                                        Wmsg_l, Wout_l, bout_l, V, Vout, h, efsum, N);
    else if (l < L-1)
      agg_update_kernel<false, true><<<2048, 256, 0, stream>>>(msrc, rowptr, eid, ssort, ef,
                                                         Wmsg_l, Wout_l, bout_l, V, Vout, h, efsum, N);
    else
      agg_update_kernel<false, false><<<2048, 256, 0, stream>>>(msrc, rowptr, eid, ssort, ef,
                                                         Wmsg_l, Wout_l, bout_l, V, Vout, h, efsum, N);
  }
}

// Round 13
// 445.554 us; speedup vs baseline: 1.0899x; 1.0899x over previous
//
#include <hip/hip_runtime.h>
#include <hip/hip_bf16.h>
#include <stdint.h>

#define H 128
#define NPB  224      // nodes per bucket
#define NBK  448      // bucket slots (NB=447 actual)
#define BCAP 6144     // max edges per bucket in LDS sort (mean ~3584)
#define NBLK 128      // partition blocks

typedef __attribute__((ext_vector_type(8))) short bf16x8;
typedef __attribute__((ext_vector_type(4))) float f32x4;

__device__ __forceinline__ unsigned pack_bf16x2(float a, float b){
  unsigned ua = __float_as_uint(a);
  unsigned ub = __float_as_uint(b);
  unsigned ra = (ua + 0x7fffu + ((ua >> 16) & 1u)) >> 16;   // RNE round to bf16
  unsigned rb = (ub + 0x7fffu + ((ub >> 16) & 1u)) >> 16;
  return ra | (rb << 16);
}
__device__ __forceinline__ float bf_lo(unsigned u){ return __uint_as_float(u << 16); }
__device__ __forceinline__ float bf_hi(unsigned u){ return __uint_as_float(u & 0xffff0000u); }

// h0 = pack_bf16(PQ @ W_in + b_in) ; V = (1,0).  h stored as bf16x2 (64 uints/node).
__global__ void init_kernel(const float* __restrict__ PQ, const float* __restrict__ Win,
                            const float* __restrict__ bin, unsigned* __restrict__ h,
                            float* __restrict__ V, int N){
  int lane = threadIdx.x & 63;
  int wid  = (blockIdx.x * blockDim.x + threadIdx.x) >> 6;
  int nw   = (gridDim.x * blockDim.x) >> 6;
  int c0 = 2*lane, c1 = c0 + 1;
  float w00 = Win[c0], w01 = Win[c1], w10 = Win[H+c0], w11 = Win[H+c1];
  float b0 = bin[c0], b1 = bin[c1];
  for (int n = wid; n < N; n += nw){
    float p0 = PQ[2*n], p1 = PQ[2*n+1];
    float h0 = p0*w00 + p1*w10 + b0;
    float h1 = p0*w01 + p1*w11 + b1;
    h[(size_t)n*64 + lane] = pack_bf16x2(h0, h1);
    if (lane == 0){ V[2*n] = 1.0f; V[2*n+1] = 0.0f; }
  }
}

// ---- atomic-free bucketed partition (radix-partition 3-pass) ----
__global__ void countA_kernel(const int* __restrict__ recv, int* __restrict__ cmat, int E){
  __shared__ int hist[NBK];
  int t = threadIdx.x;
  for (int b = t; b < NBK; b += 256) hist[b] = 0;
  __syncthreads();
  int chunk = (E + NBLK - 1) / NBLK;
  int lo = blockIdx.x * chunk, hi = min(E, lo + chunk);
  for (int i = lo + t; i < hi; i += 256)
    atomicAdd(&hist[recv[i]/NPB], 1);
  __syncthreads();
  for (int b = t; b < NBK; b += 256) cmat[blockIdx.x*NBK + b] = hist[b];
}

__global__ void cscan_kernel(const int* __restrict__ cmat, int* __restrict__ gofs,
                             int* __restrict__ bbase, int* __restrict__ rowptr,
                             int NB, int N, int E){
  __shared__ int s[512];
  int t = threadIdx.x;
  int tot = 0;
  if (t < NB)
    for (int k = 0; k < NBLK; ++k) tot += cmat[k*NBK + t];
  s[t] = tot; __syncthreads();
  #pragma unroll
  for (int off = 1; off < 512; off <<= 1){
    int x = (t >= off) ? s[t-off] : 0;
    __syncthreads();
    s[t] += x;
    __syncthreads();
  }
  int run = s[t] - tot;       // exclusive
  if (t < NB){
    bbase[t] = run;
    for (int k = 0; k < NBLK; ++k){
      gofs[k*NBK + t] = run;
      run += cmat[k*NBK + t];
    }
  }
  if (t == 0){ bbase[NB] = E; rowptr[N] = E; }
}

__global__ void scatterC_kernel(const int* __restrict__ recv, const int* __restrict__ send,
                                const int* __restrict__ gofs,
                                unsigned long long* __restrict__ ebuf, int E){
  __shared__ int cur[NBK];
  int t = threadIdx.x;
  for (int b = t; b < NBK; b += 256) cur[b] = gofs[blockIdx.x*NBK + b];
  __syncthreads();
  int chunk = (E + NBLK - 1) / NBLK;
  int lo = blockIdx.x * chunk, hi = min(E, lo + chunk);
  for (int i = lo + t; i < hi; i += 256){
    int r = recv[i];
    int b = r / NPB;
    int rloc = r - b*NPB;
    int pos = atomicAdd(&cur[b], 1);
    ebuf[pos] = ((unsigned long long)(unsigned)send[i] << 32)
              | ((unsigned long long)(unsigned)rloc << 24)
              | (unsigned long long)(unsigned)i;
  }
}

// per-bucket LDS counting sort -> dense ssort/eid + rowptr
__global__ void bsort_kernel(const unsigned long long* __restrict__ ebuf,
                             const int* __restrict__ bbase,
                             int* __restrict__ ssort, int* __restrict__ eid,
                             int* __restrict__ rowptr, int N, int NB){
  __shared__ unsigned long long se[BCAP];
  __shared__ int sdeg[256];
  __shared__ int scur[256];
  int b = blockIdx.x;
  int t = threadIdx.x;
  int base = bbase[b];
  int cnt  = bbase[b+1] - base;
  if (cnt > BCAP) cnt = BCAP;       // statistically unreachable for uniform input
  sdeg[t] = 0;
  __syncthreads();
  for (int i = t; i < cnt; i += 256){
    unsigned long long v = ebuf[base + i];
    se[i] = v;
    atomicAdd(&sdeg[(int)((v >> 24) & 0xFF)], 1);
  }
  __syncthreads();
  int own = sdeg[t];
  #pragma unroll
  for (int off = 1; off < 256; off <<= 1){
    int x = (t >= off) ? sdeg[t-off] : 0;
    __syncthreads();
    sdeg[t] += x;
    __syncthreads();
  }
  int excl = sdeg[t] - own;
  scur[t] = excl;
  int node0 = b*NPB;
  if (t < NPB && node0 + t < N) rowptr[node0 + t] = base + excl;
  __syncthreads();
  for (int i = t; i < cnt; i += 256){
    unsigned long long v = se[i];
    int off = atomicAdd(&scur[(int)((v >> 24) & 0xFF)], 1);
    ssort[base + off] = (int)(v >> 32);
    eid[base + off]   = (int)(v & 0xFFFFFF);
  }
}

// Pre-pack Wh (rows 2..129 of Wmsg) into per-lane MFMA B-fragment order, bf16x2.
__global__ void wprep_kernel(const float* __restrict__ Wmsg, unsigned* __restrict__ Wb, int L){
  int t = blockIdx.x*blockDim.x + threadIdx.x;
  if (t >= L*2048) return;
  int layer = t >> 11;
  int f = t & 2047;
  int ct   = f >> 8;
  int ks   = (f >> 6) & 3;
  int lane = f & 63;
  int col = ct*16 + (lane & 15);
  int kbase = ks*32 + (lane >> 4)*8;
  const float* Wl = Wmsg + (size_t)layer*134*H + 2*H;   // Wh rows
  unsigned u0 = pack_bf16x2(Wl[(size_t)(kbase+0)*H + col], Wl[(size_t)(kbase+1)*H + col]);
  unsigned u1 = pack_bf16x2(Wl[(size_t)(kbase+2)*H + col], Wl[(size_t)(kbase+3)*H + col]);
  unsigned u2 = pack_bf16x2(Wl[(size_t)(kbase+4)*H + col], Wl[(size_t)(kbase+5)*H + col]);
  unsigned u3 = pack_bf16x2(Wl[(size_t)(kbase+6)*H + col], Wl[(size_t)(kbase+7)*H + col]);
  uint4* dst = reinterpret_cast<uint4*>(Wb) + (size_t)layer*2048 + f;
  *dst = make_uint4(u0, u1, u2, u3);
}

// msrc = pack_bf16( h @ Wh  +  V @ Wv + b )  via MFMA (16 nodes/wave).
// Wb_l (32 KB of B fragments) staged once per block into LDS; each wave
// grid-strides over ~2 node-tiles reading B via conflict-free ds_read_b128.
__global__ void node_msg_mfma(const float* __restrict__ V, const unsigned* __restrict__ h,
                              const float* __restrict__ Wmsg_l, const float* __restrict__ bmsg_l,
                              const unsigned* __restrict__ Wb_l, unsigned* __restrict__ msrc, int N){
  __shared__ uint4 wlds[2048];            // 32 KB
  int tid = threadIdx.x;
  const uint4* wb4 = reinterpret_cast<const uint4*>(Wb_l);
  #pragma unroll
  for (int i = 0; i < 8; ++i) wlds[tid + 256*i] = wb4[tid + 256*i];
  __syncthreads();
  const bf16x8* wb = reinterpret_cast<const bf16x8*>(wlds);
  int lane = tid & 63;
  int gw   = (blockIdx.x*blockDim.x + tid) >> 6;
  int nwv  = (gridDim.x*blockDim.x) >> 6;
  int row = lane & 15, kg = lane >> 4;
  int ntiles = N >> 4;                    // N divisible by 16
  for (int t = gw; t < ntiles; t += nwv){
    int node0 = t << 4;
    const bf16x8* hrow = reinterpret_cast<const bf16x8*>(h + (size_t)(node0 + row)*64);
    bf16x8 a[4];
    #pragma unroll
    for (int ks = 0; ks < 4; ++ks) a[ks] = hrow[ks*4 + kg];
    float2 vv[4];
    #pragma unroll
    for (int r = 0; r < 4; ++r)
      vv[r] = *reinterpret_cast<const float2*>(V + 2*(node0 + kg*4 + r));
    #pragma unroll
    for (int ct = 0; ct < 8; ++ct){
      f32x4 acc = {0.f, 0.f, 0.f, 0.f};
      #pragma unroll
      for (int ks = 0; ks < 4; ++ks){
        bf16x8 b = wb[(ct*4 + ks)*64 + lane];
        acc = __builtin_amdgcn_mfma_f32_16x16x32_bf16(a[ks], b, acc, 0, 0, 0);
      }
      int col = ct*16 + row;
      float wv0 = Wmsg_l[col], wv1 = Wmsg_l[H + col], bb = bmsg_l[col];
      #pragma unroll
      for (int r = 0; r < 4; ++r){
        float o = acc[r] + vv[r].x*wv0 + vv[r].y*wv1 + bb;
        float oh = __shfl_xor(o, 1, 64);
        if (!(lane & 1)){
          int nr = node0 + kg*4 + r;
          msrc[(size_t)nr*64 + ct*8 + (row >> 1)] = pack_bf16x2(o, oh);
        }
      }
    }
  }
}

// per receiver node: acc = sum_e m_src[s_e] (+ ef term); h=relu(acc) bf16;
// dV = h@W_out + b_out; V += dV.  One wave per node; 64-edge chunks with
// full-wave broadcast gather, x4 unroll (round-11 validated structure).
template<bool FIRST, bool WRITEH>
__global__ void agg_update_kernel(const unsigned* __restrict__ msrc,
                                  const int* __restrict__ rowptr,
                                  const int* __restrict__ eid,
                                  const int* __restrict__ ssort,
                                  const float* __restrict__ ef,
                                  const float* __restrict__ Wmsg_l,
                                  const float* __restrict__ Wout_l,
                                  const float* __restrict__ bout_l,
                                  const float* __restrict__ Vin,
                                  float* __restrict__ Vout,
                                  unsigned* __restrict__ h,
                                  float4* __restrict__ efsum, int N){
  int lane = threadIdx.x & 63;
  int wid  = (blockIdx.x*blockDim.x + threadIdx.x) >> 6;
  int nw   = (gridDim.x*blockDim.x) >> 6;
  int c0 = 2*lane, c1 = c0 + 1;
  float We00 = Wmsg_l[(size_t)130*H + c0], We01 = Wmsg_l[(size_t)130*H + c1];
  float We10 = Wmsg_l[(size_t)131*H + c0], We11 = Wmsg_l[(size_t)131*H + c1];
  float We20 = Wmsg_l[(size_t)132*H + c0], We21 = Wmsg_l[(size_t)132*H + c1];
  float We30 = Wmsg_l[(size_t)133*H + c0], We31 = Wmsg_l[(size_t)133*H + c1];
  float Wo00 = Wout_l[c0*2], Wo01 = Wout_l[c0*2+1];
  float Wo10 = Wout_l[c1*2], Wo11 = Wout_l[c1*2+1];
  float bo0 = bout_l[0], bo1 = bout_l[1];
  for (int n = wid; n < N; n += nw){
    int beg = rowptr[n], end = rowptr[n+1];
    float acc0 = 0.f, acc1 = 0.f;
    float sfx = 0.f, sfy = 0.f, sfz = 0.f, sfw = 0.f;
    for (int c = beg; c < end; c += 64){
      int inlane = (c + lane < end);
      int sv = inlane ? ssort[c + lane] : 0;
      if (FIRST && inlane){
        int e = eid[c + lane];
        float4 f = *reinterpret_cast<const float4*>(ef + (size_t)e*4);
        sfx += f.x; sfy += f.y; sfz += f.z; sfw += f.w;
      }
      int kmax = min(64, end - c);
      int j = 0;
      for (; j + 4 <= kmax; j += 4){
        int s0 = __shfl(sv, j,   64);
        int s1 = __shfl(sv, j+1, 64);
        int s2 = __shfl(sv, j+2, 64);
        int s3 = __shfl(sv, j+3, 64);
        unsigned u0 = msrc[(size_t)s0*64 + lane];
        unsigned u1 = msrc[(size_t)s1*64 + lane];
        unsigned u2 = msrc[(size_t)s2*64 + lane];
        unsigned u3 = msrc[(size_t)s3*64 + lane];
        acc0 += bf_lo(u0) + bf_lo(u1) + bf_lo(u2) + bf_lo(u3);
        acc1 += bf_hi(u0) + bf_hi(u1) + bf_hi(u2) + bf_hi(u3);
      }
      for (; j < kmax; ++j){
        int s = __shfl(sv, j, 64);
        unsigned u = msrc[(size_t)s*64 + lane];
        acc0 += bf_lo(u); acc1 += bf_hi(u);
      }
    }
    if (FIRST){
      #pragma unroll
      for (int off = 32; off > 0; off >>= 1){
        sfx += __shfl_xor(sfx, off, 64);
        sfy += __shfl_xor(sfy, off, 64);
        sfz += __shfl_xor(sfz, off, 64);
        sfw += __shfl_xor(sfw, off, 64);
      }
      if (lane == 0) efsum[n] = make_float4(sfx, sfy, sfz, sfw);
    } else {
      float4 f = efsum[n];
      sfx = f.x; sfy = f.y; sfz = f.z; sfw = f.w;
    }
    acc0 += sfx*We00 + sfy*We10 + sfz*We20 + sfw*We30;
    acc1 += sfx*We01 + sfy*We11 + sfz*We21 + sfw*We31;
    float a0 = fmaxf(acc0, 0.f), a1 = fmaxf(acc1, 0.f);
    if (WRITEH) h[(size_t)n*64 + lane] = pack_bf16x2(a0, a1);
    float p0 = a0*Wo00 + a1*Wo10;
    float p1 = a0*Wo01 + a1*Wo11;
    #pragma unroll
    for (int off = 32; off > 0; off >>= 1){
      p0 += __shfl_xor(p0, off, 64);
      p1 += __shfl_xor(p1, off, 64);
    }
    if (lane == 0){
      float v0 = Vin[2*n], v1 = Vin[2*n+1];
      Vout[2*n]   = v0 + p0 + bo0;
      Vout[2*n+1] = v1 + p1 + bo1;
    }
  }
}

extern "C" void kernel_launch(void* const* d_in, const int* in_sizes, int n_in,
                              void* d_out, int out_size, void* d_ws, size_t ws_size,
                              hipStream_t stream){
  const float* PQ      = (const float*)d_in[0];
  const int*   senders = (const int*)  d_in[1];
  const int*   recv    = (const int*)  d_in[2];
  const float* ef      = (const float*)d_in[3];
  const float* Win     = (const float*)d_in[4];
  const float* bin     = (const float*)d_in[5];
  const float* Wmsg    = (const float*)d_in[6];
  const float* bmsg    = (const float*)d_in[7];
  const float* Wout    = (const float*)d_in[8];
  const float* bout    = (const float*)d_in[9];
  int N = in_sizes[0] / 2;
  int E = in_sizes[1];
  int L = in_sizes[7] / H;          // 3 layers
  int NB = (N + NPB - 1) / NPB;     // 447 buckets

  char* base = (char*)d_ws;
  size_t off = 0;
  auto alloc = [&](size_t bytes)->char*{
    char* p = base + off; off += (bytes + 255) & ~(size_t)255; return p;
  };
  unsigned* h      = (unsigned*)alloc((size_t)N*64*4);   // bf16x2-packed
  unsigned* msrc   = (unsigned*)alloc((size_t)N*64*4);
  float*    V      = (float*)   alloc((size_t)N*2*4);
  int*      rowptr = (int*)     alloc((size_t)(N+1)*4);
  int*      eid    = (int*)     alloc((size_t)E*4);
  int*      ssort  = (int*)     alloc((size_t)E*4);
  unsigned long long* ebuf = (unsigned long long*)alloc((size_t)E*8);
  float4*   efsum  = (float4*)  alloc((size_t)N*16);
  int*      cmat   = (int*)     alloc((size_t)NBLK*NBK*4);
  int*      gofs   = (int*)     alloc((size_t)NBLK*NBK*4);
  int*      bbase  = (int*)     alloc((size_t)(NB+1)*4);
  unsigned* Wb     = (unsigned*)alloc((size_t)L*2048*16); // MFMA B fragments
  if (off > ws_size) return;

  init_kernel<<<2048, 256, 0, stream>>>(PQ, Win, bin, h, V, N);
  countA_kernel<<<NBLK, 256, 0, stream>>>(recv, cmat, E);
  cscan_kernel<<<1, 512, 0, stream>>>(cmat, gofs, bbase, rowptr, NB, N, E);
  scatterC_kernel<<<NBLK, 256, 0, stream>>>(recv, senders, gofs, ebuf, E);
  bsort_kernel<<<NB, 256, 0, stream>>>(ebuf, bbase, ssort, eid, rowptr, N, NB);
  wprep_kernel<<<(L*2048 + 255)/256, 256, 0, stream>>>(Wmsg, Wb, L);

  for (int l = 0; l < L; ++l){
    const float* Wmsg_l = Wmsg + (size_t)l*134*H;
    const float* bmsg_l = bmsg + (size_t)l*H;
    const float* Wout_l = Wout + (size_t)l*H*2;
    const float* bout_l = bout + (size_t)l*2;
    const unsigned* Wb_l = Wb + (size_t)l*2048*4;
    node_msg_mfma<<<784, 256, 0, stream>>>(V, h, Wmsg_l, bmsg_l, Wb_l, msrc, N);
    float* Vout = (l == L-1) ? (float*)d_out : V;
    if (l == 0)
      agg_update_kernel<true, true><<<2048, 256, 0, stream>>>(msrc, rowptr, eid, ssort, ef,
                                                        Wmsg_l, Wout_l, bout_l, V, Vout, h, efsum, N);
    else if (l < L-1)
      agg_update_kernel<false, true><<<2048, 256, 0, stream>>>(msrc, rowptr, eid, ssort, ef,
                                                         Wmsg_l, Wout_l, bout_l, V, Vout, h, efsum, N);
    else
      agg_update_kernel<false, false><<<2048, 256, 0, stream>>>(msrc, rowptr, eid, ssort, ef,
                                                         Wmsg_l, Wout_l, bout_l, V, Vout, h, efsum, N);
  }
}

// Round 14
// 402.131 us; speedup vs baseline: 1.2075x; 1.1080x over previous
//
#include <hip/hip_runtime.h>
#include <hip/hip_bf16.h>
#include <stdint.h>

#define H 128
#define NPB  224      // nodes per bucket
#define NBK  448      // bucket slots (NB=447 actual)
#define BCAP 6144     // max edges per bucket in LDS sort (mean ~3584)
#define NBLK 128      // partition blocks

typedef __attribute__((ext_vector_type(8))) short bf16x8;
typedef __attribute__((ext_vector_type(4))) float f32x4;

__device__ __forceinline__ unsigned pack_bf16x2(float a, float b){
  unsigned ua = __float_as_uint(a);
  unsigned ub = __float_as_uint(b);
  unsigned ra = (ua + 0x7fffu + ((ua >> 16) & 1u)) >> 16;   // RNE round to bf16
  unsigned rb = (ub + 0x7fffu + ((ub >> 16) & 1u)) >> 16;
  return ra | (rb << 16);
}
__device__ __forceinline__ float bf_lo(unsigned u){ return __uint_as_float(u << 16); }
__device__ __forceinline__ float bf_hi(unsigned u){ return __uint_as_float(u & 0xffff0000u); }

// ---- atomic-free bucketed partition (radix-partition 3-pass) ----
__global__ void countA_kernel(const int* __restrict__ recv, int* __restrict__ cmat, int E){
  __shared__ int hist[NBK];
  int t = threadIdx.x;
  for (int b = t; b < NBK; b += 256) hist[b] = 0;
  __syncthreads();
  int chunk = (E + NBLK - 1) / NBLK;
  int lo = blockIdx.x * chunk, hi = min(E, lo + chunk);
  for (int i = lo + t; i < hi; i += 256)
    atomicAdd(&hist[recv[i]/NPB], 1);
  __syncthreads();
  for (int b = t; b < NBK; b += 256) cmat[blockIdx.x*NBK + b] = hist[b];
}

__global__ void cscan_kernel(const int* __restrict__ cmat, int* __restrict__ gofs,
                             int* __restrict__ bbase, int* __restrict__ rowptr,
                             int NB, int N, int E){
  __shared__ int s[512];
  int t = threadIdx.x;
  int tot = 0;
  if (t < NB)
    for (int k = 0; k < NBLK; ++k) tot += cmat[k*NBK + t];
  s[t] = tot; __syncthreads();
  #pragma unroll
  for (int off = 1; off < 512; off <<= 1){
    int x = (t >= off) ? s[t-off] : 0;
    __syncthreads();
    s[t] += x;
    __syncthreads();
  }
  int run = s[t] - tot;       // exclusive
  if (t < NB){
    bbase[t] = run;
    for (int k = 0; k < NBLK; ++k){
      gofs[k*NBK + t] = run;
      run += cmat[k*NBK + t];
    }
  }
  if (t == 0){ bbase[NB] = E; rowptr[N] = E; }
}

__global__ void scatterC_kernel(const int* __restrict__ recv, const int* __restrict__ send,
                                const int* __restrict__ gofs,
                                unsigned long long* __restrict__ ebuf, int E){
  __shared__ int cur[NBK];
  int t = threadIdx.x;
  for (int b = t; b < NBK; b += 256) cur[b] = gofs[blockIdx.x*NBK + b];
  __syncthreads();
  int chunk = (E + NBLK - 1) / NBLK;
  int lo = blockIdx.x * chunk, hi = min(E, lo + chunk);
  for (int i = lo + t; i < hi; i += 256){
    int r = recv[i];
    int b = r / NPB;
    int rloc = r - b*NPB;
    int pos = atomicAdd(&cur[b], 1);
    ebuf[pos] = ((unsigned long long)(unsigned)send[i] << 32)
              | ((unsigned long long)(unsigned)rloc << 24)
              | (unsigned long long)(unsigned)i;
  }
}

// per-bucket LDS counting sort -> dense ssort/eid + rowptr
__global__ void bsort_kernel(const unsigned long long* __restrict__ ebuf,
                             const int* __restrict__ bbase,
                             int* __restrict__ ssort, int* __restrict__ eid,
                             int* __restrict__ rowptr, int N, int NB){
  __shared__ unsigned long long se[BCAP];
  __shared__ int sdeg[256];
  __shared__ int scur[256];
  int b = blockIdx.x;
  int t = threadIdx.x;
  int base = bbase[b];
  int cnt  = bbase[b+1] - base;
  if (cnt > BCAP) cnt = BCAP;       // statistically unreachable for uniform input
  sdeg[t] = 0;
  __syncthreads();
  for (int i = t; i < cnt; i += 256){
    unsigned long long v = ebuf[base + i];
    se[i] = v;
    atomicAdd(&sdeg[(int)((v >> 24) & 0xFF)], 1);
  }
  __syncthreads();
  int own = sdeg[t];
  #pragma unroll
  for (int off = 1; off < 256; off <<= 1){
    int x = (t >= off) ? sdeg[t-off] : 0;
    __syncthreads();
    sdeg[t] += x;
    __syncthreads();
  }
  int excl = sdeg[t] - own;
  scur[t] = excl;
  int node0 = b*NPB;
  if (t < NPB && node0 + t < N) rowptr[node0 + t] = base + excl;
  __syncthreads();
  for (int i = t; i < cnt; i += 256){
    unsigned long long v = se[i];
    int off = atomicAdd(&scur[(int)((v >> 24) & 0xFF)], 1);
    ssort[base + off] = (int)(v >> 32);
    eid[base + off]   = (int)(v & 0xFFFFFF);
  }
}

// Pre-pack Wh (rows 2..129 of Wmsg) into per-lane MFMA B-fragment order, bf16x2.
__global__ void wprep_kernel(const float* __restrict__ Wmsg, unsigned* __restrict__ Wb, int L){
  int t = blockIdx.x*blockDim.x + threadIdx.x;
  if (t >= L*2048) return;
  int layer = t >> 11;
  int f = t & 2047;
  int ct   = f >> 8;
  int ks   = (f >> 6) & 3;
  int lane = f & 63;
  int col = ct*16 + (lane & 15);
  int kbase = ks*32 + (lane >> 4)*8;
  const float* Wl = Wmsg + (size_t)layer*134*H + 2*H;   // Wh rows
  unsigned u0 = pack_bf16x2(Wl[(size_t)(kbase+0)*H + col], Wl[(size_t)(kbase+1)*H + col]);
  unsigned u1 = pack_bf16x2(Wl[(size_t)(kbase+2)*H + col], Wl[(size_t)(kbase+3)*H + col]);
  unsigned u2 = pack_bf16x2(Wl[(size_t)(kbase+4)*H + col], Wl[(size_t)(kbase+5)*H + col]);
  unsigned u3 = pack_bf16x2(Wl[(size_t)(kbase+6)*H + col], Wl[(size_t)(kbase+7)*H + col]);
  uint4* dst = reinterpret_cast<uint4*>(Wb) + (size_t)layer*2048 + f;
  *dst = make_uint4(u0, u1, u2, u3);
}

// Layer-0 analytic fold: msrc0 = PQ0*A0 + PQ1*A1 + C  where
// A_i[c] = sum_k Win[i][k] * Wh[k][c],  C[c] = sum_k bin[k]*Wh[k][c] + Wv[0][c] + bmsg[c]
// (V0 = (1,0) constant, h0 = PQ@Win + bin never materialized).  fp32 exact.
__global__ void prep0_kernel(const float* __restrict__ Wmsg, const float* __restrict__ bmsg,
                             const float* __restrict__ Win, const float* __restrict__ bin,
                             float* __restrict__ ACC){
  int c = threadIdx.x;                 // 128 threads
  const float* Wh = Wmsg + 2*H;
  float a0 = 0.f, a1 = 0.f, cc = 0.f;
  for (int k = 0; k < H; ++k){
    float w = Wh[(size_t)k*H + c];
    a0 += Win[k]     * w;
    a1 += Win[H + k] * w;
    cc += bin[k]     * w;
  }
  cc += Wmsg[c] + bmsg[c];             // + Wv[0][c]*1 + Wv[1][c]*0 + bias
  ACC[c] = a0; ACC[H + c] = a1; ACC[2*H + c] = cc;
}

__global__ void msrc0_kernel(const float* __restrict__ PQ, const float* __restrict__ ACC,
                             unsigned* __restrict__ msrc, int N){
  int lane = threadIdx.x & 63;
  int wid  = (blockIdx.x*blockDim.x + threadIdx.x) >> 6;
  int nw   = (gridDim.x*blockDim.x) >> 6;
  int c0 = 2*lane, c1 = c0 + 1;
  float A00 = ACC[c0], A01 = ACC[c1];
  float A10 = ACC[H + c0], A11 = ACC[H + c1];
  float C0  = ACC[2*H + c0], C1 = ACC[2*H + c1];
  for (int n = wid; n < N; n += nw){
    float2 pq = *reinterpret_cast<const float2*>(PQ + 2*n);
    msrc[(size_t)n*64 + lane] = pack_bf16x2(pq.x*A00 + pq.y*A10 + C0,
                                            pq.x*A01 + pq.y*A11 + C1);
  }
}

// msrc = pack_bf16( h @ Wh  +  V @ Wv + b )  via MFMA (16 nodes/wave).
// Wb_l (32 KB of B fragments) staged once per block into LDS.
__global__ void node_msg_mfma(const float* __restrict__ V, const unsigned* __restrict__ h,
                              const float* __restrict__ Wmsg_l, const float* __restrict__ bmsg_l,
                              const unsigned* __restrict__ Wb_l, unsigned* __restrict__ msrc, int N){
  __shared__ uint4 wlds[2048];            // 32 KB
  int tid = threadIdx.x;
  const uint4* wb4 = reinterpret_cast<const uint4*>(Wb_l);
  #pragma unroll
  for (int i = 0; i < 8; ++i) wlds[tid + 256*i] = wb4[tid + 256*i];
  __syncthreads();
  const bf16x8* wb = reinterpret_cast<const bf16x8*>(wlds);
  int lane = tid & 63;
  int gw   = (blockIdx.x*blockDim.x + tid) >> 6;
  int nwv  = (gridDim.x*blockDim.x) >> 6;
  int row = lane & 15, kg = lane >> 4;
  int ntiles = N >> 4;                    // N divisible by 16
  for (int t = gw; t < ntiles; t += nwv){
    int node0 = t << 4;
    const bf16x8* hrow = reinterpret_cast<const bf16x8*>(h + (size_t)(node0 + row)*64);
    bf16x8 a[4];
    #pragma unroll
    for (int ks = 0; ks < 4; ++ks) a[ks] = hrow[ks*4 + kg];
    float2 vv[4];
    #pragma unroll
    for (int r = 0; r < 4; ++r)
      vv[r] = *reinterpret_cast<const float2*>(V + 2*(node0 + kg*4 + r));
    #pragma unroll
    for (int ct = 0; ct < 8; ++ct){
      f32x4 acc = {0.f, 0.f, 0.f, 0.f};
      #pragma unroll
      for (int ks = 0; ks < 4; ++ks){
        bf16x8 b = wb[(ct*4 + ks)*64 + lane];
        acc = __builtin_amdgcn_mfma_f32_16x16x32_bf16(a[ks], b, acc, 0, 0, 0);
      }
      int col = ct*16 + row;
      float wv0 = Wmsg_l[col], wv1 = Wmsg_l[H + col], bb = bmsg_l[col];
      #pragma unroll
      for (int r = 0; r < 4; ++r){
        float o = acc[r] + vv[r].x*wv0 + vv[r].y*wv1 + bb;
        float oh = __shfl_xor(o, 1, 64);
        if (!(lane & 1)){
          int nr = node0 + kg*4 + r;
          msrc[(size_t)nr*64 + ct*8 + (row >> 1)] = pack_bf16x2(o, oh);
        }
      }
    }
  }
}

// per receiver node: acc = sum_e m_src[s_e] (+ ef term); h=relu(acc) bf16;
// dV = h@W_out + b_out; V += dV.  One wave per node; 64-edge chunks with
// full-wave broadcast gather, x4 unroll (round-11 validated structure).
// FIRST: Vin = (1,0) constant, gathers ef, writes efsum.
template<bool FIRST, bool WRITEH>
__global__ void agg_update_kernel(const unsigned* __restrict__ msrc,
                                  const int* __restrict__ rowptr,
                                  const int* __restrict__ eid,
                                  const int* __restrict__ ssort,
                                  const float* __restrict__ ef,
                                  const float* __restrict__ Wmsg_l,
                                  const float* __restrict__ Wout_l,
                                  const float* __restrict__ bout_l,
                                  const float* __restrict__ Vin,
                                  float* __restrict__ Vout,
                                  unsigned* __restrict__ h,
                                  float4* __restrict__ efsum, int N){
  int lane = threadIdx.x & 63;
  int wid  = (blockIdx.x*blockDim.x + threadIdx.x) >> 6;
  int nw   = (gridDim.x*blockDim.x) >> 6;
  int c0 = 2*lane, c1 = c0 + 1;
  float We00 = Wmsg_l[(size_t)130*H + c0], We01 = Wmsg_l[(size_t)130*H + c1];
  float We10 = Wmsg_l[(size_t)131*H + c0], We11 = Wmsg_l[(size_t)131*H + c1];
  float We20 = Wmsg_l[(size_t)132*H + c0], We21 = Wmsg_l[(size_t)132*H + c1];
  float We30 = Wmsg_l[(size_t)133*H + c0], We31 = Wmsg_l[(size_t)133*H + c1];
  float Wo00 = Wout_l[c0*2], Wo01 = Wout_l[c0*2+1];
  float Wo10 = Wout_l[c1*2], Wo11 = Wout_l[c1*2+1];
  float bo0 = bout_l[0], bo1 = bout_l[1];
  for (int n = wid; n < N; n += nw){
    int beg = rowptr[n], end = rowptr[n+1];
    float acc0 = 0.f, acc1 = 0.f;
    float sfx = 0.f, sfy = 0.f, sfz = 0.f, sfw = 0.f;
    for (int c = beg; c < end; c += 64){
      int inlane = (c + lane < end);
      int sv = inlane ? ssort[c + lane] : 0;
      if (FIRST && inlane){
        int e = eid[c + lane];
        float4 f = *reinterpret_cast<const float4*>(ef + (size_t)e*4);
        sfx += f.x; sfy += f.y; sfz += f.z; sfw += f.w;
      }
      int kmax = min(64, end - c);
      int j = 0;
      for (; j + 4 <= kmax; j += 4){
        int s0 = __shfl(sv, j,   64);
        int s1 = __shfl(sv, j+1, 64);
        int s2 = __shfl(sv, j+2, 64);
        int s3 = __shfl(sv, j+3, 64);
        unsigned u0 = msrc[(size_t)s0*64 + lane];
        unsigned u1 = msrc[(size_t)s1*64 + lane];
        unsigned u2 = msrc[(size_t)s2*64 + lane];
        unsigned u3 = msrc[(size_t)s3*64 + lane];
        acc0 += bf_lo(u0) + bf_lo(u1) + bf_lo(u2) + bf_lo(u3);
        acc1 += bf_hi(u0) + bf_hi(u1) + bf_hi(u2) + bf_hi(u3);
      }
      for (; j < kmax; ++j){
        int s = __shfl(sv, j, 64);
        unsigned u = msrc[(size_t)s*64 + lane];
        acc0 += bf_lo(u); acc1 += bf_hi(u);
      }
    }
    if (FIRST){
      #pragma unroll
      for (int off = 32; off > 0; off >>= 1){
        sfx += __shfl_xor(sfx, off, 64);
        sfy += __shfl_xor(sfy, off, 64);
        sfz += __shfl_xor(sfz, off, 64);
        sfw += __shfl_xor(sfw, off, 64);
      }
      if (lane == 0) efsum[n] = make_float4(sfx, sfy, sfz, sfw);
    } else {
      float4 f = efsum[n];
      sfx = f.x; sfy = f.y; sfz = f.z; sfw = f.w;
    }
    acc0 += sfx*We00 + sfy*We10 + sfz*We20 + sfw*We30;
    acc1 += sfx*We01 + sfy*We11 + sfz*We21 + sfw*We31;
    float a0 = fmaxf(acc0, 0.f), a1 = fmaxf(acc1, 0.f);
    if (WRITEH) h[(size_t)n*64 + lane] = pack_bf16x2(a0, a1);
    float p0 = a0*Wo00 + a1*Wo10;
    float p1 = a0*Wo01 + a1*Wo11;
    #pragma unroll
    for (int off = 16; off > 0; off >>= 1){
      p0 += __shfl_xor(p0, off, 64);
      p1 += __shfl_xor(p1, off, 64);
    }
    p0 += __shfl_xor(p0, 32, 64);
    p1 += __shfl_xor(p1, 32, 64);
    if (lane == 0){
      float v0, v1;
      if (FIRST){ v0 = 1.0f; v1 = 0.0f; }
      else      { v0 = Vin[2*n]; v1 = Vin[2*n+1]; }
      Vout[2*n]   = v0 + p0 + bo0;
      Vout[2*n+1] = v1 + p1 + bo1;
    }
  }
}

extern "C" void kernel_launch(void* const* d_in, const int* in_sizes, int n_in,
                              void* d_out, int out_size, void* d_ws, size_t ws_size,
                              hipStream_t stream){
  const float* PQ      = (const float*)d_in[0];
  const int*   senders = (const int*)  d_in[1];
  const int*   recv    = (const int*)  d_in[2];
  const float* ef      = (const float*)d_in[3];
  const float* Win     = (const float*)d_in[4];
  const float* bin     = (const float*)d_in[5];
  const float* Wmsg    = (const float*)d_in[6];
  const float* bmsg    = (const float*)d_in[7];
  const float* Wout    = (const float*)d_in[8];
  const float* bout    = (const float*)d_in[9];
  int N = in_sizes[0] / 2;
  int E = in_sizes[1];
  int L = in_sizes[7] / H;          // 3 layers
  int NB = (N + NPB - 1) / NPB;     // 447 buckets

  char* base = (char*)d_ws;
  size_t off = 0;
  auto alloc = [&](size_t bytes)->char*{
    char* p = base + off; off += (bytes + 255) & ~(size_t)255; return p;
  };
  unsigned* h      = (unsigned*)alloc((size_t)N*64*4);   // bf16x2-packed
  unsigned* msrc   = (unsigned*)alloc((size_t)N*64*4);
  float*    V      = (float*)   alloc((size_t)N*2*4);
  int*      rowptr = (int*)     alloc((size_t)(N+1)*4);
  int*      eid    = (int*)     alloc((size_t)E*4);
  int*      ssort  = (int*)     alloc((size_t)E*4);
  unsigned long long* ebuf = (unsigned long long*)alloc((size_t)E*8);
  float4*   efsum  = (float4*)  alloc((size_t)N*16);
  int*      cmat   = (int*)     alloc((size_t)NBLK*NBK*4);
  int*      gofs   = (int*)     alloc((size_t)NBLK*NBK*4);
  int*      bbase  = (int*)     alloc((size_t)(NB+1)*4);
  unsigned* Wb     = (unsigned*)alloc((size_t)L*2048*16); // MFMA B fragments
  float*    ACC0   = (float*)   alloc((size_t)3*H*4);     // layer-0 fold
  if (off > ws_size) return;

  countA_kernel<<<NBLK, 256, 0, stream>>>(recv, cmat, E);
  cscan_kernel<<<1, 512, 0, stream>>>(cmat, gofs, bbase, rowptr, NB, N, E);
  scatterC_kernel<<<NBLK, 256, 0, stream>>>(recv, senders, gofs, ebuf, E);
  bsort_kernel<<<NB, 256, 0, stream>>>(ebuf, bbase, ssort, eid, rowptr, N, NB);
  wprep_kernel<<<(L*2048 + 255)/256, 256, 0, stream>>>(Wmsg, Wb, L);
  prep0_kernel<<<1, H, 0, stream>>>(Wmsg, bmsg, Win, bin, ACC0);
  msrc0_kernel<<<2048, 256, 0, stream>>>(PQ, ACC0, msrc, N);

  for (int l = 0; l < L; ++l){
    const float* Wmsg_l = Wmsg + (size_t)l*134*H;
    const float* bmsg_l = bmsg + (size_t)l*H;
    const float* Wout_l = Wout + (size_t)l*H*2;
    const float* bout_l = bout + (size_t)l*2;
    const unsigned* Wb_l = Wb + (size_t)l*2048*4;
    if (l > 0)
      node_msg_mfma<<<784, 256, 0, stream>>>(V, h, Wmsg_l, bmsg_l, Wb_l, msrc, N);
    float* Vout = (l == L-1) ? (float*)d_out : V;
    if (l == 0)
      agg_update_kernel<true, true><<<2048, 256, 0, stream>>>(msrc, rowptr, eid, ssort, ef,
                                                        Wmsg_l, Wout_l, bout_l, V, Vout, h, efsum, N);
    else if (l < L-1)
      agg_update_kernel<false, true><<<2048, 256, 0, stream>>>(msrc, rowptr, eid, ssort, ef,
                                                         Wmsg_l, Wout_l, bout_l, V, Vout, h, efsum, N);
    else
      agg_update_kernel<false, false><<<2048, 256, 0, stream>>>(msrc, rowptr, eid, ssort, ef,
                                                         Wmsg_l, Wout_l, bout_l, V, Vout, h, efsum, N);
  }
}